// Round 5
// baseline (1924.072 us; speedup 1.0000x reference)
//
#include <hip/hip_runtime.h>

#define NROWS 8192
#define RPB   64
#define TPB   1024     // 16 waves/block, 128 blocks, 1 block/CU (LDS-bound)
#define NBLK  128

typedef float v4f __attribute__((ext_vector_type(4)));

// workspace layout (float offsets)
#define OFF_W1   0          // 1024
#define OFF_W2   1024       // 1024
#define OFF_WIN  2048       // 102*34 = 3468
#define OFF_WFC2 5516       // 1024
#define OFF_M    6540       // 32*34 = 1088
#define OFF_B12  7628       // 32
#define OFF_BIN  7660       // 102
#define OFF_B2   7762       // 32
#define OFF_BFC2 7794       // 32
#define OFF_LNG  7826       // 32
#define OFF_LNB  7858       // 32
#define OFF_BAR  7904       // 128 ints (per-BLOCK arrival flags, monotonic)
#define OFF_QKV0 8192
#define QKVN     (NROWS*102)          // feature-major: qkv[e][row]
#define OFF_QKV1 (OFF_QKV0 + QKVN)

__global__ __launch_bounds__(256) void setup_kernel(
    const float* __restrict__ W_x2h, const float* __restrict__ b_x2h,
    const float* __restrict__ W_h2h, const float* __restrict__ b_h2h,
    const float* __restrict__ W_fc2, const float* __restrict__ b_fc2,
    const float* __restrict__ ln_g,  const float* __restrict__ ln_b,
    const float* __restrict__ W_fcsa,const float* __restrict__ b_fcsa,
    const float* __restrict__ W_in,  const float* __restrict__ b_in,
    const float* __restrict__ W_out, const float* __restrict__ b_out,
    float* __restrict__ ws)
{
  int t = blockIdx.x*blockDim.x + threadIdx.x;
  int stride = gridDim.x*blockDim.x;
  for (int i=t;i<1024;i+=stride) ws[OFF_W1+i]   = W_x2h[i];
  for (int i=t;i<1024;i+=stride) ws[OFF_W2+i]   = W_h2h[i];
  for (int i=t;i<3468;i+=stride) ws[OFF_WIN+i]  = W_in[i];
  for (int i=t;i<1024;i+=stride) ws[OFF_WFC2+i] = W_fc2[i];
  for (int i=t;i<32;i+=stride)   ws[OFF_B12+i]  = b_x2h[i] + b_h2h[i];
  for (int i=t;i<102;i+=stride)  ws[OFF_BIN+i]  = b_in[i];
  for (int i=t;i<32;i+=stride)   ws[OFF_BFC2+i] = b_fc2[i];
  for (int i=t;i<32;i+=stride)   ws[OFF_LNG+i]  = ln_g[i];
  for (int i=t;i<32;i+=stride)   ws[OFF_LNB+i]  = ln_b[i];
  // zero per-block arrival flags (re-zeroed every launch/graph replay)
  for (int i=t;i<128;i+=stride)  ((int*)(ws+OFF_BAR))[i] = 0;
  // M = W_fcsa (32x34) @ W_out (34x34)
  for (int idx=t; idx<1088; idx+=stride) {
    int j = idx/34, f = idx - j*34;
    float acc = 0.f;
    for (int e=0;e<34;++e)
      acc += W_fcsa[j*34+e] * W_out[e*34+f];
    ws[OFF_M+idx] = acc;
  }
  for (int j=t;j<32;j+=stride){
    float acc = b_fcsa[j];
    for (int e=0;e<34;++e) acc += W_fcsa[j*34+e] * b_out[e];
    ws[OFF_B2+j] = acc;
  }
}

// Persistent kernel, all 60 steps in one regular launch (128 blocks x 130KB LDS
// -> 1 block/CU, co-resident by construction).
//
// R4 lesson: agent-scope ATOMICS are correct but serialize (each ~800cy IF
// round trip, no batching) and the single barrier counter is 128 serialized
// RMWs. This round: same IF-coherent exchange, but
//  - staged loads = inline-asm global_load_dwordx4 sc0 sc1, all issued before
//    ONE s_waitcnt vmcnt(0) -> ~1 IF latency instead of ~13
//  - only k,v cross blocks (q is consumed locally; only grid-rows 1/62's q is
//    needed by the 4 shifted-boundary blocks)
//  - publish = fire-and-forget global_store sc0 sc1 (drained at syncthreads)
//  - barrier = per-block flag (monotonic step number, plain store) + wave-0
//    polls all 128 flags -> no RMW convoy
__global__ __launch_bounds__(TPB) void fused_kernel(
    float* __restrict__ ws,
    const float* __restrict__ x,
    float* __restrict__ out)
{
  const float* W1f   = ws + OFF_W1;
  const float* W2f   = ws + OFF_W2;
  const float* Winf  = ws + OFF_WIN;
  const float* Wfc2f = ws + OFF_WFC2;
  const float* Mf    = ws + OFF_M;
  const float* b12f  = ws + OFF_B12;
  const float* binf  = ws + OFF_BIN;
  const float* b2f   = ws + OFF_B2;
  const float* bfc2f = ws + OFF_BFC2;
  const float* lngf  = ws + OFF_LNG;
  const float* lnbf  = ws + OFF_LNB;
  int*   bar = (int*)(ws + OFF_BAR);
  float* q0  = ws + OFF_QKV0;
  float* q1  = ws + OFF_QKV1;

  __shared__ __align__(16) float sQKV[3][102][64]; // qkv rows (br-1,br,br+1)
  __shared__ float sS[RPB][13];      // 9 scores (stride 13: conflict-free)
  __shared__ float sO[RPB][35];      // attention output (34)
  __shared__ float sHp[RPB][33];     // h' (persistent across steps)
  __shared__ float sG[RPB][33];      // pre-LN fc2 output
  __shared__ float sPred[RPB][33];   // pred (next-step input, persistent)
  __shared__ float sHn[RPB][33];     // h_new (tanh output, persistent)
  __shared__ float sX[RPB][33];      // staged x chunk (steps 0..9)

  const int tid = threadIdx.x;
  const int lr  = tid & 63;
  const int wu  = __builtin_amdgcn_readfirstlane(tid >> 6);  // wave id 0..15
  const int base= blockIdx.x * RPB;
  const int r   = base + lr;
  // block covers exactly one (batch, grid-row); gc == lr
  const int bb  = base >> 12;                    // uniform
  const int grb = (base & 4095) >> 6;            // uniform (unclamped, for pl)
  const int brb = (grb < 1) ? 1 : ((grb > 62) ? 62 : grb);  // uniform clamp
  const int bc  = (lr < 1) ? 1 : ((lr > 62) ? 62 : lr);     // per-lane col clamp
  const int rb0 = (bb << 12) + ((brb - 1) << 6); // global row of stage slot 0
  const int own_slot = grb - brb + 1;            // which slot is OUR grid-row
  const int slotA = (own_slot == 0) ? 1 : 0;     // the two neighbor slots
  const int slotB = (own_slot == 2) ? 1 : 2;
  const int lrow4 = (lr & 15) << 2;              // row-group within 64 (x4)
  const int lfhi  = lr >> 4;                     // feature sub-index 0..3

  for (int i = 0; i < 60; ++i) {
    const int stepB = i - 1;
    const int stepA = (i <= 58) ? i : -1;
    float* qR = ((i + 1) & 1) ? q1 : q0;         // qkv of step i-1 (read)
    float* qW = (i & 1) ? q1 : q0;               // qkv of step i (write)

    // ---- phase 0: stage neighbor k,v into LDS (batched sc0sc1 float4) ----
    if (stepB >= 0) {
      v4f vals[3]; int cslot[3], cfeat[3];
      #pragma unroll
      for (int it = 0; it < 3; ++it) {
        int c = wu + 16*it;                      // wave-uniform chunk 0..33
        cfeat[it] = -1;
        if (c < 34) {
          int half = (c >= 17);
          int cs   = c - (half ? 17 : 0);        // 0..16
          int feat = 34 + cs*4 + lfhi;           // 34..101 (k,v only)
          int slot = half ? slotB : slotA;
          const float* ga = qR + (size_t)feat*NROWS + rb0 + (slot<<6) + lrow4;
          asm volatile("global_load_dwordx4 %0, %1, off sc0 sc1"
                       : "=v"(vals[it]) : "v"(ga) : "memory");
          cslot[it] = slot; cfeat[it] = feat;
        }
      }
      // boundary blocks also need slot-1's q (scores query = shifted center)
      v4f qv = {0.f,0.f,0.f,0.f}; int qfeat = -1;
      if (own_slot != 1 && wu < 9) {
        int feat = wu*4 + lfhi;                  // 0..35, per-lane
        if (feat < 34) {                          // divergent tail guard
          const float* ga = qR + (size_t)feat*NROWS + rb0 + (1<<6) + lrow4;
          asm volatile("global_load_dwordx4 %0, %1, off sc0 sc1"
                       : "=v"(qv) : "v"(ga) : "memory");
          qfeat = feat;
        }
      }
      asm volatile("s_waitcnt vmcnt(0)" ::: "memory");
      __builtin_amdgcn_sched_barrier(0);
      #pragma unroll
      for (int it = 0; it < 3; ++it)
        if (cfeat[it] >= 0)
          *(v4f*)&sQKV[cslot[it]][cfeat[it]][lrow4] = vals[it];
      if (qfeat >= 0)
        *(v4f*)&sQKV[1][qfeat][lrow4] = qv;
    } else {
      // step 0: h' = 0
      sHp[lr][2*wu] = 0.f; sHp[lr][2*wu+1] = 0.f;
    }
    if (stepA >= 0 && stepA < 10) {
      size_t xbase = ((size_t)stepA*NROWS + base)*32;
      #pragma unroll
      for (int it = 0; it < 2; ++it) {
        int idx = tid + it*TPB;
        sX[idx>>5][idx&31] = x[xbase + idx];
      }
    }
    __syncthreads();

    if (stepB >= 0) {
      // ---- phase 1: scores (waves 0..8, m=wu) — pure LDS ----
      if (wu < 9) {
        const int slot = wu / 3;                 // uniform
        const int col  = bc + (wu - slot*3 - 1); // 0..63
        float acc = 0.f;
        #pragma unroll
        for (int e = 0; e < 34; ++e)
          acc += sQKV[1][e][bc] * sQKV[slot][34+e][col];
        sS[lr][wu] = acc * 0.1714985851425088f;  // 1/sqrt(34)
      }
      __syncthreads();
      // ---- phase 2: softmax (redundant per wave) + o slice — pure LDS ----
      {
        float sc[9]; float mx = -1e30f;
        #pragma unroll
        for (int m=0;m<9;++m){ sc[m]=sS[lr][m]; mx=fmaxf(mx,sc[m]); }
        float sum=0.f;
        #pragma unroll
        for (int m=0;m<9;++m){ sc[m]=__expf(sc[m]-mx); sum+=sc[m]; }
        float inv = 1.f/sum;
        float o0=0.f, o1=0.f, o2=0.f;
        const bool e2ok = (wu < 2);              // wave-uniform
        #pragma unroll
        for (int m=0;m<9;++m){
          const int slot = m/3;
          const int col  = bc + (m - slot*3 - 1);
          float wm = sc[m]*inv;
          o0 += wm * sQKV[slot][68+wu][col];
          o1 += wm * sQKV[slot][84+wu][col];
          if (e2ok) o2 += wm * sQKV[slot][100+wu][col];
        }
        sO[lr][wu]    = o0;
        sO[lr][wu+16] = o1;
        if (e2ok) sO[lr][wu+32] = o2;
      }
      __syncthreads();
      // ---- phase 3: h' = h_new(LDS) + o @ M^T + b2 : wave wu -> j=2wu,2wu+1 ----
      {
        const int j0 = wu*2;
        float a0 = b2f[j0], a1 = b2f[j0+1];
        #pragma unroll
        for (int e=0;e<34;++e){
          float ov = sO[lr][e];
          a0 += ov * Mf[j0*34+e];                // s_load weights
          a1 += ov * Mf[(j0+1)*34+e];
        }
        sHp[lr][j0]   = sHn[lr][j0]   + a0;
        sHp[lr][j0+1] = sHn[lr][j0+1] + a1;
      }
      __syncthreads();
      // ---- phase 4: g = h' @ Wfc2^T + b ----
      {
        const int j0 = wu*2;
        float g0 = bfc2f[j0], g1 = bfc2f[j0+1];
        #pragma unroll
        for (int ii=0;ii<32;++ii){
          float hv = sHp[lr][ii];
          g0 += hv * Wfc2f[j0*32+ii];            // s_load
          g1 += hv * Wfc2f[(j0+1)*32+ii];
        }
        sG[lr][j0]=g0; sG[lr][j0+1]=g1;
      }
      __syncthreads();
      // ---- phase 5: layernorm -> sPred ----
      {
        float mu=0.f;
        #pragma unroll
        for (int ii=0;ii<32;++ii) mu += sG[lr][ii];
        mu *= 0.03125f;
        float var=0.f;
        #pragma unroll
        for (int ii=0;ii<32;++ii){ float d=sG[lr][ii]-mu; var += d*d; }
        var *= 0.03125f;
        float rs = rsqrtf(var + 1e-5f);
        const int j0 = wu*2;
        sPred[lr][j0]   = (sG[lr][j0]  -mu)*rs*lngf[j0]   + lnbf[j0];
        sPred[lr][j0+1] = (sG[lr][j0+1]-mu)*rs*lngf[j0+1] + lnbf[j0+1];
      }
      __syncthreads();
      // ---- coalesced out write (block chunk is 2048 contiguous floats) ----
      {
        size_t obase = ((size_t)stepB*NROWS + base)*32;
        #pragma unroll
        for (int it=0; it<2; ++it){
          int idx = tid + it*TPB;
          out[obase + idx] = sPred[idx>>5][idx&31];
        }
      }
    }

    if (stepA >= 0) {
      // ---- h_new = tanh(inp@W1^T + h'@W2^T + b) : wave wu -> j=2wu,2wu+1 ----
      const int j0 = wu*2;
      float a0=b12f[j0], a1=b12f[j0+1];
      if (stepA < 10) {
        #pragma unroll
        for (int ii=0;ii<32;++ii){
          float xv=sX[lr][ii], hv=sHp[lr][ii];
          a0 += xv*W1f[j0*32+ii]     + hv*W2f[j0*32+ii];     // s_load
          a1 += xv*W1f[(j0+1)*32+ii] + hv*W2f[(j0+1)*32+ii];
        }
      } else {
        #pragma unroll
        for (int ii=0;ii<32;++ii){
          float xv=sPred[lr][ii], hv=sHp[lr][ii];
          a0 += xv*W1f[j0*32+ii]     + hv*W2f[j0*32+ii];     // s_load
          a1 += xv*W1f[(j0+1)*32+ii] + hv*W2f[(j0+1)*32+ii];
        }
      }
      {
        float t0 = tanhf(a0), t1 = tanhf(a1);
        sHn[lr][j0]=t0; sHn[lr][j0+1]=t1;       // stays in LDS (no global!)
      }
      __syncthreads();
      // ---- qkv = [h_new, pl] @ W_in^T + b_in : wave wu -> e = wu + 16k ----
      float hn[32];
      #pragma unroll
      for (int f=0;f<32;++f) hn[f]=sHn[lr][f];
      const float pl0 = grb*0.015625f, pl1 = lr*0.015625f;
      const bool pubq = (grb == 1) || (grb == 62);  // rows read as shifted centers
      #pragma unroll
      for (int k=0;k<7;++k){
        int e = wu + 16*k;                       // wave-uniform
        if (e < 102) {
          float acc = binf[e];
          #pragma unroll
          for (int f=0;f<32;++f) acc += hn[f]*Winf[e*34+f];  // s_load
          acc += pl0*Winf[e*34+32] + pl1*Winf[e*34+33];
          // publish k,v (and q only from rows 1/62): write-through to IF,
          // fire-and-forget (drained by the barrier's syncthreads)
          if (e >= 34 || pubq) {
            float* ga = qW + (size_t)e*NROWS + r;
            asm volatile("global_store_dword %0, %1, off sc0 sc1"
                         :: "v"(ga), "v"(acc) : "memory");
          }
          // own copy in LDS (next step's own_slot — no re-read)
          sQKV[own_slot][e][lr] = acc;
        }
      }
    }

    // ---- flag-array grid barrier (no RMW convoy) ----
    if (i < 59) {
      __syncthreads();                  // all publishes drained (vmcnt 0)
      if (tid == 0)
        __hip_atomic_store(&bar[blockIdx.x], i+1, __ATOMIC_RELAXED,
                           __HIP_MEMORY_SCOPE_AGENT);
      if (wu == 0) {                    // wave 0 polls all 128 flags
        int polls = 0; bool ok = false;
        do {
          int f0 = __hip_atomic_load(&bar[lr],    __ATOMIC_RELAXED,
                                     __HIP_MEMORY_SCOPE_AGENT);
          int f1 = __hip_atomic_load(&bar[lr+64], __ATOMIC_RELAXED,
                                     __HIP_MEMORY_SCOPE_AGENT);
          ok = (f0 > i) && (f1 > i);
          if (!ok) __builtin_amdgcn_s_sleep(1);
        } while (!__all(ok) && ++polls < (1<<20));
      }
      __syncthreads();
    }
  }
}

extern "C" void kernel_launch(void* const* d_in, const int* in_sizes, int n_in,
                              void* d_out, int out_size, void* d_ws, size_t ws_size,
                              hipStream_t stream) {
  const float* x     = (const float*)d_in[0];
  const float* W_x2h = (const float*)d_in[1];
  const float* b_x2h = (const float*)d_in[2];
  const float* W_h2h = (const float*)d_in[3];
  const float* b_h2h = (const float*)d_in[4];
  const float* W_fc2 = (const float*)d_in[5];
  const float* b_fc2 = (const float*)d_in[6];
  const float* ln_g  = (const float*)d_in[7];
  const float* ln_b  = (const float*)d_in[8];
  const float* W_fcsa= (const float*)d_in[9];
  const float* b_fcsa= (const float*)d_in[10];
  const float* W_in  = (const float*)d_in[11];
  const float* b_in  = (const float*)d_in[12];
  const float* W_out = (const float*)d_in[13];
  const float* b_out = (const float*)d_in[14];
  float* ws = (float*)d_ws;
  float* out = (float*)d_out;

  setup_kernel<<<8, 256, 0, stream>>>(W_x2h,b_x2h,W_h2h,b_h2h,W_fc2,b_fc2,ln_g,ln_b,
                                      W_fcsa,b_fcsa,W_in,b_in,W_out,b_out, ws);
  fused_kernel<<<NBLK, TPB, 0, stream>>>(ws, x, out);
}

// Round 6
// 1747.902 us; speedup vs baseline: 1.1008x; 1.1008x over previous
//
#include <hip/hip_runtime.h>

#define NROWS 8192
#define RPB   64
#define TPB   1024     // 16 waves/block, 128 blocks, 1 block/CU (LDS-bound)
#define NBLK  128

typedef float v4f __attribute__((ext_vector_type(4)));

// workspace layout (float offsets)
#define OFF_W1   0          // 1024
#define OFF_W2   1024       // 1024
#define OFF_WIN  2048       // 102*34 = 3468
#define OFF_WFC2 5516       // 1024
#define OFF_M    6540       // 32*34 = 1088
#define OFF_B12  7628       // 32
#define OFF_BIN  7660       // 102
#define OFF_B2   7762       // 32
#define OFF_BFC2 7794       // 32
#define OFF_LNG  7826       // 32
#define OFF_LNB  7858       // 32
#define OFF_BAR  7904       // 128 ints (per-BLOCK arrival flags, monotonic)
#define OFF_QKV0 8192
#define QKVN     (NROWS*102)          // feature-major: qkv[e][row]
#define OFF_QKV1 (OFF_QKV0 + QKVN)

__global__ __launch_bounds__(256) void setup_kernel(
    const float* __restrict__ W_x2h, const float* __restrict__ b_x2h,
    const float* __restrict__ W_h2h, const float* __restrict__ b_h2h,
    const float* __restrict__ W_fc2, const float* __restrict__ b_fc2,
    const float* __restrict__ ln_g,  const float* __restrict__ ln_b,
    const float* __restrict__ W_fcsa,const float* __restrict__ b_fcsa,
    const float* __restrict__ W_in,  const float* __restrict__ b_in,
    const float* __restrict__ W_out, const float* __restrict__ b_out,
    float* __restrict__ ws)
{
  int t = blockIdx.x*blockDim.x + threadIdx.x;
  int stride = gridDim.x*blockDim.x;
  for (int i=t;i<1024;i+=stride) ws[OFF_W1+i]   = W_x2h[i];
  for (int i=t;i<1024;i+=stride) ws[OFF_W2+i]   = W_h2h[i];
  for (int i=t;i<3468;i+=stride) ws[OFF_WIN+i]  = W_in[i];
  for (int i=t;i<1024;i+=stride) ws[OFF_WFC2+i] = W_fc2[i];
  for (int i=t;i<32;i+=stride)   ws[OFF_B12+i]  = b_x2h[i] + b_h2h[i];
  for (int i=t;i<102;i+=stride)  ws[OFF_BIN+i]  = b_in[i];
  for (int i=t;i<32;i+=stride)   ws[OFF_BFC2+i] = b_fc2[i];
  for (int i=t;i<32;i+=stride)   ws[OFF_LNG+i]  = ln_g[i];
  for (int i=t;i<32;i+=stride)   ws[OFF_LNB+i]  = ln_b[i];
  // zero per-block arrival flags (re-zeroed every launch/graph replay)
  for (int i=t;i<128;i+=stride)  ((int*)(ws+OFF_BAR))[i] = 0;
  // M = W_fcsa (32x34) @ W_out (34x34)
  for (int idx=t; idx<1088; idx+=stride) {
    int j = idx/34, f = idx - j*34;
    float acc = 0.f;
    for (int e=0;e<34;++e)
      acc += W_fcsa[j*34+e] * W_out[e*34+f];
    ws[OFF_M+idx] = acc;
  }
  for (int j=t;j<32;j+=stride){
    float acc = b_fcsa[j];
    for (int e=0;e<34;++e) acc += W_fcsa[j*34+e] * b_out[e];
    ws[OFF_B2+j] = acc;
  }
}

// Persistent kernel, all 60 steps in one regular launch (128 blocks x 130KB LDS
// -> 1 block/CU, co-resident by construction).
//
// R5 lesson: the GLOBAL barrier was the invariant ~31us/step cost — 128 blocks
// polling the same flag lines through the IF every step (poll storm + convoy).
// The dependency graph is a 1-D chain (block g needs only grid-rows g-1,g,g+1,
// same batch), so this round replaces the global barrier with a NEIGHBOR-ONLY
// handshake: monotonic per-block flags; thread 0 waits on exactly 2 dep flags.
// Adjacent-block skew is bounded to 1 step => the qkv double buffer is safe:
// dep flag >= i  ==>  dep finished iter i-1, hence done STAGING step i-2 data
// (so our parity-(i&1) write can't clobber an in-flight read), and its step
// i-1 publish is drained (vmcnt(0) at its pre-flag syncthreads).
// Publish is vectorized from LDS: 1088 coalesced global_store_dwordx4 sc0 sc1
// per block instead of ~4600 scalar sc-stores (cuts uncached-write transactions
// and the WRITE_SIZE amplification R5 exposed).
__global__ __launch_bounds__(TPB) void fused_kernel(
    float* __restrict__ ws,
    const float* __restrict__ x,
    float* __restrict__ out)
{
  const float* W1f   = ws + OFF_W1;
  const float* W2f   = ws + OFF_W2;
  const float* Winf  = ws + OFF_WIN;
  const float* Wfc2f = ws + OFF_WFC2;
  const float* Mf    = ws + OFF_M;
  const float* b12f  = ws + OFF_B12;
  const float* binf  = ws + OFF_BIN;
  const float* b2f   = ws + OFF_B2;
  const float* bfc2f = ws + OFF_BFC2;
  const float* lngf  = ws + OFF_LNG;
  const float* lnbf  = ws + OFF_LNB;
  int*   bar = (int*)(ws + OFF_BAR);
  float* q0  = ws + OFF_QKV0;
  float* q1  = ws + OFF_QKV1;

  __shared__ __align__(16) float sQKV[3][102][64]; // qkv rows (br-1,br,br+1)
  __shared__ float sS[RPB][13];      // 9 scores (stride 13: conflict-free)
  __shared__ float sO[RPB][35];      // attention output (34)
  __shared__ float sHp[RPB][33];     // h' (persistent across steps)
  __shared__ float sG[RPB][33];      // pre-LN fc2 output
  __shared__ float sPred[RPB][33];   // pred (next-step input, persistent)
  __shared__ float sHn[RPB][33];     // h_new (tanh output, persistent)
  __shared__ float sX[RPB][33];      // staged x chunk (steps 0..9)

  const int tid = threadIdx.x;
  const int lr  = tid & 63;
  const int wu  = __builtin_amdgcn_readfirstlane(tid >> 6);  // wave id 0..15
  const int base= blockIdx.x * RPB;
  const int r   = base + lr;
  // block covers exactly one (batch, grid-row); gc == lr
  const int bb  = base >> 12;                    // uniform
  const int grb = (base & 4095) >> 6;            // uniform (unclamped, for pl)
  const int brb = (grb < 1) ? 1 : ((grb > 62) ? 62 : grb);  // uniform clamp
  const int bc  = (lr < 1) ? 1 : ((lr > 62) ? 62 : lr);     // per-lane col clamp
  const int rb0 = (bb << 12) + ((brb - 1) << 6); // global row of stage slot 0
  const int own_slot = grb - brb + 1;            // which slot is OUR grid-row
  const int slotA = (own_slot == 0) ? 1 : 0;     // the two neighbor slots
  const int slotB = (own_slot == 2) ? 1 : 2;
  const int lrow4 = (lr & 15) << 2;              // row-group within 64 (x4)
  const int lfhi  = lr >> 4;                     // feature sub-index 0..3
  // dependency blocks (rows of slotA/slotB in this batch)
  const int depA = (bb << 6) + (brb - 1) + slotA;
  const int depB = (bb << 6) + (brb - 1) + slotB;
  const bool pubq = (grb == 1) || (grb == 62);   // rows read as shifted centers

  for (int i = 0; i < 60; ++i) {
    const int stepB = i - 1;
    const int stepA = (i <= 58) ? i : -1;
    float* qR = ((i + 1) & 1) ? q1 : q0;         // qkv of step i-1 (read)
    float* qW = (i & 1) ? q1 : q0;               // qkv of step i (write)

    // ---- neighbor handshake: wait for the 2 dep rows to finish iter i-1 ----
    if (i > 0) {
      if (tid == 0) {
        int polls = 0;
        for (;;) {
          int fa = __hip_atomic_load(&bar[depA], __ATOMIC_RELAXED,
                                     __HIP_MEMORY_SCOPE_AGENT);
          int fb = __hip_atomic_load(&bar[depB], __ATOMIC_RELAXED,
                                     __HIP_MEMORY_SCOPE_AGENT);
          if ((fa >= i && fb >= i) || ++polls >= (1<<16)) break;
          __builtin_amdgcn_s_sleep(2);
        }
      }
      __syncthreads();
    }

    // ---- phase 0: stage neighbor k,v into LDS (batched sc0sc1 float4) ----
    if (stepB >= 0) {
      v4f vals[3]; int cslot[3], cfeat[3];
      #pragma unroll
      for (int it = 0; it < 3; ++it) {
        int c = wu + 16*it;                      // wave-uniform chunk 0..33
        cfeat[it] = -1;
        if (c < 34) {
          int half = (c >= 17);
          int cs   = c - (half ? 17 : 0);        // 0..16
          int feat = 34 + cs*4 + lfhi;           // 34..101 (k,v only)
          int slot = half ? slotB : slotA;
          const float* ga = qR + (size_t)feat*NROWS + rb0 + (slot<<6) + lrow4;
          asm volatile("global_load_dwordx4 %0, %1, off sc0 sc1"
                       : "=v"(vals[it]) : "v"(ga) : "memory");
          cslot[it] = slot; cfeat[it] = feat;
        }
      }
      // boundary blocks also need slot-1's q (scores query = shifted center)
      v4f qv = {0.f,0.f,0.f,0.f}; int qfeat = -1;
      if (own_slot != 1 && wu < 9) {
        int feat = wu*4 + lfhi;                  // 0..35, per-lane
        if (feat < 34) {                          // divergent tail guard
          const float* ga = qR + (size_t)feat*NROWS + rb0 + (1<<6) + lrow4;
          asm volatile("global_load_dwordx4 %0, %1, off sc0 sc1"
                       : "=v"(qv) : "v"(ga) : "memory");
          qfeat = feat;
        }
      }
      asm volatile("s_waitcnt vmcnt(0)" ::: "memory");
      __builtin_amdgcn_sched_barrier(0);
      #pragma unroll
      for (int it = 0; it < 3; ++it)
        if (cfeat[it] >= 0)
          *(v4f*)&sQKV[cslot[it]][cfeat[it]][lrow4] = vals[it];
      if (qfeat >= 0)
        *(v4f*)&sQKV[1][qfeat][lrow4] = qv;
    } else {
      // step 0: h' = 0
      sHp[lr][2*wu] = 0.f; sHp[lr][2*wu+1] = 0.f;
    }
    if (stepA >= 0 && stepA < 10) {
      size_t xbase = ((size_t)stepA*NROWS + base)*32;
      #pragma unroll
      for (int it = 0; it < 2; ++it) {
        int idx = tid + it*TPB;
        sX[idx>>5][idx&31] = x[xbase + idx];
      }
    }
    __syncthreads();

    if (stepB >= 0) {
      // ---- phase 1: scores (waves 0..8, m=wu) — pure LDS ----
      if (wu < 9) {
        const int slot = wu / 3;                 // uniform
        const int col  = bc + (wu - slot*3 - 1); // 0..63
        float acc = 0.f;
        #pragma unroll
        for (int e = 0; e < 34; ++e)
          acc += sQKV[1][e][bc] * sQKV[slot][34+e][col];
        sS[lr][wu] = acc * 0.1714985851425088f;  // 1/sqrt(34)
      }
      __syncthreads();
      // ---- phase 2: softmax (redundant per wave) + o slice — pure LDS ----
      {
        float sc[9]; float mx = -1e30f;
        #pragma unroll
        for (int m=0;m<9;++m){ sc[m]=sS[lr][m]; mx=fmaxf(mx,sc[m]); }
        float sum=0.f;
        #pragma unroll
        for (int m=0;m<9;++m){ sc[m]=__expf(sc[m]-mx); sum+=sc[m]; }
        float inv = 1.f/sum;
        float o0=0.f, o1=0.f, o2=0.f;
        const bool e2ok = (wu < 2);              // wave-uniform
        #pragma unroll
        for (int m=0;m<9;++m){
          const int slot = m/3;
          const int col  = bc + (m - slot*3 - 1);
          float wm = sc[m]*inv;
          o0 += wm * sQKV[slot][68+wu][col];
          o1 += wm * sQKV[slot][84+wu][col];
          if (e2ok) o2 += wm * sQKV[slot][100+wu][col];
        }
        sO[lr][wu]    = o0;
        sO[lr][wu+16] = o1;
        if (e2ok) sO[lr][wu+32] = o2;
      }
      __syncthreads();
      // ---- phase 3: h' = h_new(LDS) + o @ M^T + b2 : wave wu -> j=2wu,2wu+1 ----
      {
        const int j0 = wu*2;
        float a0 = b2f[j0], a1 = b2f[j0+1];
        #pragma unroll
        for (int e=0;e<34;++e){
          float ov = sO[lr][e];
          a0 += ov * Mf[j0*34+e];                // s_load weights
          a1 += ov * Mf[(j0+1)*34+e];
        }
        sHp[lr][j0]   = sHn[lr][j0]   + a0;
        sHp[lr][j0+1] = sHn[lr][j0+1] + a1;
      }
      __syncthreads();
      // ---- phase 4: g = h' @ Wfc2^T + b ----
      {
        const int j0 = wu*2;
        float g0 = bfc2f[j0], g1 = bfc2f[j0+1];
        #pragma unroll
        for (int ii=0;ii<32;++ii){
          float hv = sHp[lr][ii];
          g0 += hv * Wfc2f[j0*32+ii];            // s_load
          g1 += hv * Wfc2f[(j0+1)*32+ii];
        }
        sG[lr][j0]=g0; sG[lr][j0+1]=g1;
      }
      __syncthreads();
      // ---- phase 5: layernorm -> sPred ----
      {
        float mu=0.f;
        #pragma unroll
        for (int ii=0;ii<32;++ii) mu += sG[lr][ii];
        mu *= 0.03125f;
        float var=0.f;
        #pragma unroll
        for (int ii=0;ii<32;++ii){ float d=sG[lr][ii]-mu; var += d*d; }
        var *= 0.03125f;
        float rs = rsqrtf(var + 1e-5f);
        const int j0 = wu*2;
        sPred[lr][j0]   = (sG[lr][j0]  -mu)*rs*lngf[j0]   + lnbf[j0];
        sPred[lr][j0+1] = (sG[lr][j0+1]-mu)*rs*lngf[j0+1] + lnbf[j0+1];
      }
      __syncthreads();
      // ---- coalesced out write (block chunk is 2048 contiguous floats) ----
      {
        size_t obase = ((size_t)stepB*NROWS + base)*32;
        #pragma unroll
        for (int it=0; it<2; ++it){
          int idx = tid + it*TPB;
          out[obase + idx] = sPred[idx>>5][idx&31];
        }
      }
    }

    if (stepA >= 0) {
      // ---- h_new = tanh(inp@W1^T + h'@W2^T + b) : wave wu -> j=2wu,2wu+1 ----
      const int j0 = wu*2;
      float a0=b12f[j0], a1=b12f[j0+1];
      if (stepA < 10) {
        #pragma unroll
        for (int ii=0;ii<32;++ii){
          float xv=sX[lr][ii], hv=sHp[lr][ii];
          a0 += xv*W1f[j0*32+ii]     + hv*W2f[j0*32+ii];     // s_load
          a1 += xv*W1f[(j0+1)*32+ii] + hv*W2f[(j0+1)*32+ii];
        }
      } else {
        #pragma unroll
        for (int ii=0;ii<32;++ii){
          float xv=sPred[lr][ii], hv=sHp[lr][ii];
          a0 += xv*W1f[j0*32+ii]     + hv*W2f[j0*32+ii];     // s_load
          a1 += xv*W1f[(j0+1)*32+ii] + hv*W2f[(j0+1)*32+ii];
        }
      }
      {
        float t0 = tanhf(a0), t1 = tanhf(a1);
        sHn[lr][j0]=t0; sHn[lr][j0+1]=t1;       // stays in LDS (no global!)
      }
      __syncthreads();
      // ---- qkv = [h_new, pl] @ W_in^T + b_in -> LDS only ----
      float hn[32];
      #pragma unroll
      for (int f=0;f<32;++f) hn[f]=sHn[lr][f];
      const float pl0 = grb*0.015625f, pl1 = lr*0.015625f;
      #pragma unroll
      for (int k=0;k<7;++k){
        int e = wu + 16*k;                       // wave-uniform
        if (e < 102) {
          float acc = binf[e];
          #pragma unroll
          for (int f=0;f<32;++f) acc += hn[f]*Winf[e*34+f];  // s_load
          acc += pl0*Winf[e*34+32] + pl1*Winf[e*34+33];
          sQKV[own_slot][e][lr] = acc;           // LDS only (publish below)
        }
      }
      __syncthreads();
      // ---- vectorized publish from LDS (coalesced dwordx4, write-through) ----
      {
        {
          int feat = 34 + (tid >> 4);            // 34..97
          int rg   = (tid & 15) << 2;
          v4f v = *(const v4f*)&sQKV[own_slot][feat][rg];
          float* ga = qW + (size_t)feat*NROWS + base + rg;
          asm volatile("global_store_dwordx4 %0, %1, off sc0 sc1"
                       :: "v"(ga), "v"(v) : "memory");
        }
        if (tid < 64) {
          int feat = 98 + (tid >> 4);            // 98..101
          int rg   = (tid & 15) << 2;
          v4f v = *(const v4f*)&sQKV[own_slot][feat][rg];
          float* ga = qW + (size_t)feat*NROWS + base + rg;
          asm volatile("global_store_dwordx4 %0, %1, off sc0 sc1"
                       :: "v"(ga), "v"(v) : "memory");
        }
        if (pubq && tid < 544) {
          int feat = tid >> 4;                   // 0..33 (q, boundary rows only)
          int rg   = (tid & 15) << 2;
          v4f v = *(const v4f*)&sQKV[own_slot][feat][rg];
          float* ga = qW + (size_t)feat*NROWS + base + rg;
          asm volatile("global_store_dwordx4 %0, %1, off sc0 sc1"
                       :: "v"(ga), "v"(v) : "memory");
        }
      }
      // drain publishes (each wave waits vmcnt(0) before s_barrier), then flag
      __syncthreads();
      if (tid == 0)
        __hip_atomic_store(&bar[blockIdx.x], i + 1, __ATOMIC_RELAXED,
                           __HIP_MEMORY_SCOPE_AGENT);
    }
  }
}

extern "C" void kernel_launch(void* const* d_in, const int* in_sizes, int n_in,
                              void* d_out, int out_size, void* d_ws, size_t ws_size,
                              hipStream_t stream) {
  const float* x     = (const float*)d_in[0];
  const float* W_x2h = (const float*)d_in[1];
  const float* b_x2h = (const float*)d_in[2];
  const float* W_h2h = (const float*)d_in[3];
  const float* b_h2h = (const float*)d_in[4];
  const float* W_fc2 = (const float*)d_in[5];
  const float* b_fc2 = (const float*)d_in[6];
  const float* ln_g  = (const float*)d_in[7];
  const float* ln_b  = (const float*)d_in[8];
  const float* W_fcsa= (const float*)d_in[9];
  const float* b_fcsa= (const float*)d_in[10];
  const float* W_in  = (const float*)d_in[11];
  const float* b_in  = (const float*)d_in[12];
  const float* W_out = (const float*)d_in[13];
  const float* b_out = (const float*)d_in[14];
  float* ws = (float*)d_ws;
  float* out = (float*)d_out;

  setup_kernel<<<8, 256, 0, stream>>>(W_x2h,b_x2h,W_h2h,b_h2h,W_fc2,b_fc2,ln_g,ln_b,
                                      W_fcsa,b_fcsa,W_in,b_in,W_out,b_out, ws);
  fused_kernel<<<NBLK, TPB, 0, stream>>>(ws, x, out);
}

// Round 10
// 962.592 us; speedup vs baseline: 1.9988x; 1.8158x over previous
//
#include <hip/hip_runtime.h>

#define NROWS 8192
#define RPB   32       // rows per block
#define TPB   1024     // 16 waves; slot = tid>>5 (0..31), row = tid&31
#define NBLK  256      // every CU gets a block

// workspace layout (float offsets) — identical to the passing R1 kernel
#define OFF_W1   0          // 1024
#define OFF_W2   1024       // 1024
#define OFF_WIN  2048       // 102*34 = 3468
#define OFF_WFC2 5516       // 1024
#define OFF_M    6540       // 32*34 = 1088
#define OFF_B12  7628       // 32
#define OFF_BIN  7660       // 102
#define OFF_B2   7762       // 32
#define OFF_BFC2 7794       // 32
#define OFF_LNG  7826       // 32
#define OFF_LNB  7858       // 32
#define OFF_QKV0 8192
#define QKVN     (NROWS*102)          // feature-major: qkv[e][row]
#define OFF_QKV1 (OFF_QKV0 + QKVN)
#define OFF_HNEW (OFF_QKV1 + QKVN)   // feature-major: hnew[j][row], 32*NROWS

__global__ __launch_bounds__(256) void setup_kernel(
    const float* __restrict__ W_x2h, const float* __restrict__ b_x2h,
    const float* __restrict__ W_h2h, const float* __restrict__ b_h2h,
    const float* __restrict__ W_fc2, const float* __restrict__ b_fc2,
    const float* __restrict__ ln_g,  const float* __restrict__ ln_b,
    const float* __restrict__ W_fcsa,const float* __restrict__ b_fcsa,
    const float* __restrict__ W_in,  const float* __restrict__ b_in,
    const float* __restrict__ W_out, const float* __restrict__ b_out,
    float* __restrict__ ws)
{
  int t = blockIdx.x*blockDim.x + threadIdx.x;
  int stride = gridDim.x*blockDim.x;
  for (int i=t;i<1024;i+=stride) ws[OFF_W1+i]   = W_x2h[i];
  for (int i=t;i<1024;i+=stride) ws[OFF_W2+i]   = W_h2h[i];
  for (int i=t;i<3468;i+=stride) ws[OFF_WIN+i]  = W_in[i];
  for (int i=t;i<1024;i+=stride) ws[OFF_WFC2+i] = W_fc2[i];
  for (int i=t;i<32;i+=stride)   ws[OFF_B12+i]  = b_x2h[i] + b_h2h[i];
  for (int i=t;i<102;i+=stride)  ws[OFF_BIN+i]  = b_in[i];
  for (int i=t;i<32;i+=stride)   ws[OFF_BFC2+i] = b_fc2[i];
  for (int i=t;i<32;i+=stride)   ws[OFF_LNG+i]  = ln_g[i];
  for (int i=t;i<32;i+=stride)   ws[OFF_LNB+i]  = ln_b[i];
  // M = W_fcsa (32x34) @ W_out (34x34)
  for (int idx=t; idx<1088; idx+=stride) {
    int j = idx/34, f = idx - j*34;
    float acc = 0.f;
    for (int e=0;e<34;++e)
      acc += W_fcsa[j*34+e] * W_out[e*34+f];
    ws[OFF_M+idx] = acc;
  }
  for (int j=t;j<32;j+=stride){
    float acc = b_fcsa[j];
    for (int e=0;e<34;++e) acc += W_fcsa[j*34+e] * b_out[e];
    ws[OFF_B2+j] = acc;
  }
}

// Multi-launch step kernel (R1 structure, re-partitioned to fill all 256 CUs):
// 32 rows/block, 256 blocks, 1024 threads. slot = tid>>5 (0..31) is the
// feature/work slot; row = tid&31. Weight indices are no longer wave-uniform
// (slot varies within a wave), so weights are staged into LDS once per launch
// (~8 coalesced L2-hot loads/thread); LDS weight reads are 2-lane broadcasts
// (free). All state flows through LDS within the launch; hnew/qkv through
// global between launches (launch-boundary coherence — no custom sync).
__global__ __launch_bounds__(TPB) void step_kernel(
    const float* __restrict__ ws,
    const float* __restrict__ qkvR,     // qkv of step stepB (read)
    float* __restrict__ qkvW,           // qkv of step stepA (write)
    float* __restrict__ hnewG,          // feature-major tanh-state
    const float* __restrict__ x,
    float* __restrict__ out,
    int stepB, int stepA)
{
  __shared__ float sW1[32][32], sW2[32][32], sWfc2[32][32];
  __shared__ float sM[32][36];       // 36: 16B-aligned rows
  __shared__ float sWin[102][36];
  __shared__ float sB12[32], sBin[102], sB2[32], sBfc2[32], sLng[32], sLnb[32];
  __shared__ float sS[RPB][13];      // 9 scores (odd stride: conflict-free)
  __shared__ float sO[RPB][35];      // attention output (34)
  __shared__ float sHp[RPB][33];     // h' (prestaged hnew + attention)
  __shared__ float sG[RPB][33];      // pre-LN fc2 output
  __shared__ float sPred[RPB][33];   // pred (next-step input)
  __shared__ float sHn[RPB][33];     // h_new (tanh output)
  __shared__ float sX[RPB][33];      // staged x chunk (steps 0..9)

  const int tid  = threadIdx.x;
  const int lr2  = tid & 31;         // row within block
  const int slot = tid >> 5;         // work slot 0..31
  const int base = blockIdx.x * RPB;
  const int r2   = base + lr2;
  const int b    = base >> 12;       // batch (uniform)
  const int p    = base & 4095;
  const int gr   = p >> 6;           // grid-row (uniform)
  const int gc0  = p & 63;           // 0 or 32 (uniform)
  const int c    = gc0 + lr2;        // global column (per-lane)
  const int br   = (gr < 1) ? 1 : ((gr > 62) ? 62 : gr);
  const int bc   = (c  < 1) ? 1 : ((c  > 62) ? 62 : c);

  // ---- phase A (no deps, fully concurrent): stage weights/biases + x,
  //      prestage hnew (slots 16..31), scores (slots 0..8) ----
  {
    sW1  [tid>>5][tid&31] = ws[OFF_W1  +tid];
    sW2  [tid>>5][tid&31] = ws[OFF_W2  +tid];
    sWfc2[tid>>5][tid&31] = ws[OFF_WFC2+tid];
    for (int idx=tid; idx<1088; idx+=TPB){ int j=idx/34, e=idx-j*34; sM[j][e]=ws[OFF_M+idx]; }
    for (int idx=tid; idx<3468; idx+=TPB){ int e=idx/34, f=idx-e*34; sWin[e][f]=ws[OFF_WIN+idx]; }
    if (tid < 102)                    sBin [tid]     = ws[OFF_BIN +tid];
    else if (tid>=128 && tid<160)     sB12 [tid-128] = ws[OFF_B12 +tid-128];
    else if (tid>=160 && tid<192)     sB2  [tid-160] = ws[OFF_B2  +tid-160];
    else if (tid>=192 && tid<224)     sBfc2[tid-192] = ws[OFF_BFC2+tid-192];
    else if (tid>=224 && tid<256)     sLng [tid-224] = ws[OFF_LNG +tid-224];
    else if (tid>=256 && tid<288)     sLnb [tid-256] = ws[OFF_LNB +tid-256];
  }
  if (stepA >= 0 && stepA < 10) {
    size_t xbase = ((size_t)stepA*NROWS + base)*32;
    sX[tid>>5][tid&31] = x[xbase + tid];           // 1024 floats, coalesced
  }
  if (stepB >= 0) {
    if (slot >= 16) {                               // prestage hnew -> sHp
      const int j0 = (slot-16)*2;
      sHp[lr2][j0]   = hnewG[(size_t)j0    *NROWS + r2];
      sHp[lr2][j0+1] = hnewG[(size_t)(j0+1)*NROWS + r2];
    } else if (slot < 9) {                          // scores, m = slot
      const int m  = slot;
      const int dr = m/3 - 1, dc = m - (m/3)*3 - 1;
      const int qrow = (b<<12) + (br<<6) + bc;
      const int nr_  = (b<<12) + ((br+dr)<<6) + (bc+dc);
      float acc = 0.f;
      #pragma unroll
      for (int e=0;e<34;++e)
        acc += qkvR[(size_t)e*NROWS + qrow] * qkvR[(size_t)(34+e)*NROWS + nr_];
      sS[lr2][m] = acc * 0.1714985851425088f;       // 1/sqrt(34)
    }
  } else {
    sHp[lr2][slot] = 0.f;                           // step 0: h' = 0
  }
  __syncthreads();

  if (stepB >= 0) {
    // ---- softmax (redundant per slot) + o feature(s) ----
    {
      float sc[9]; float mx = -1e30f;
      #pragma unroll
      for (int m=0;m<9;++m){ sc[m]=sS[lr2][m]; mx=fmaxf(mx,sc[m]); }
      float sum=0.f;
      #pragma unroll
      for (int m=0;m<9;++m){ sc[m]=__expf(sc[m]-mx); sum+=sc[m]; }
      float inv = 1.f/sum;
      float o0=0.f, o1=0.f;
      const bool e2ok = (slot < 2);
      #pragma unroll
      for (int m=0;m<9;++m){
        int dr = m/3 - 1, dc = m - (m/3)*3 - 1;
        int nr_ = (b<<12) + ((br+dr)<<6) + (bc+dc);
        float wm = sc[m]*inv;
        o0 += wm * qkvR[(size_t)(68+slot)*NROWS + nr_];
        if (e2ok) o1 += wm * qkvR[(size_t)(100+slot)*NROWS + nr_];
      }
      sO[lr2][slot] = o0;
      if (e2ok) sO[lr2][32+slot] = o1;
    }
    __syncthreads();
    // ---- h' = hnew(prestaged) + o @ M^T + b2 : slot -> j = slot ----
    {
      float a = sB2[slot];
      #pragma unroll
      for (int e=0;e<34;++e) a += sO[lr2][e] * sM[slot][e];
      sHp[lr2][slot] += a;
    }
    __syncthreads();
    // ---- g = h' @ Wfc2^T + b ----
    {
      float g = sBfc2[slot];
      #pragma unroll
      for (int i=0;i<32;++i) g += sHp[lr2][i] * sWfc2[slot][i];
      sG[lr2][slot] = g;
    }
    __syncthreads();
    // ---- layernorm -> sPred ----
    {
      float mu=0.f;
      #pragma unroll
      for (int i=0;i<32;++i) mu += sG[lr2][i];
      mu *= 0.03125f;
      float var=0.f;
      #pragma unroll
      for (int i=0;i<32;++i){ float d=sG[lr2][i]-mu; var += d*d; }
      var *= 0.03125f;
      float rs = rsqrtf(var + 1e-5f);
      sPred[lr2][slot] = (sG[lr2][slot]-mu)*rs*sLng[slot] + sLnb[slot];
    }
    __syncthreads();
    // ---- coalesced out write (block chunk = 1024 contiguous floats) ----
    {
      size_t obase = ((size_t)stepB*NROWS + base)*32;
      out[obase + tid] = sPred[tid>>5][tid&31];
    }
  } else {
    __syncthreads(); __syncthreads(); __syncthreads(); __syncthreads();
  }

  if (stepA >= 0) {
    // ---- h_new = tanh(inp@W1^T + h'@W2^T + b) : slot -> j = slot ----
    float a = sB12[slot];
    if (stepA < 10) {
      #pragma unroll
      for (int i=0;i<32;++i)
        a += sX[lr2][i]*sW1[slot][i] + sHp[lr2][i]*sW2[slot][i];
    } else {
      #pragma unroll
      for (int i=0;i<32;++i)
        a += sPred[lr2][i]*sW1[slot][i] + sHp[lr2][i]*sW2[slot][i];
    }
    {
      float t0 = tanhf(a);
      sHn[lr2][slot] = t0;
      hnewG[(size_t)slot*NROWS + r2] = t0;          // 128B segments per slot
    }
    __syncthreads();
    // ---- qkv = [h_new, pl] @ W_in^T + b_in : slot -> e = slot + 32k ----
    float hn[32];
    #pragma unroll
    for (int f=0;f<32;++f) hn[f]=sHn[lr2][f];
    const float pl0 = gr*0.015625f, pl1 = c*0.015625f;
    #pragma unroll
    for (int k=0;k<4;++k){
      int e = slot + 32*k;
      if (e < 102) {
        float acc = sBin[e];
        #pragma unroll
        for (int f=0;f<32;++f) acc += hn[f]*sWin[e][f];
        acc += pl0*sWin[e][32] + pl1*sWin[e][33];
        qkvW[(size_t)e*NROWS + r2] = acc;           // 128B segments per e
      }
    }
  }
}

extern "C" void kernel_launch(void* const* d_in, const int* in_sizes, int n_in,
                              void* d_out, int out_size, void* d_ws, size_t ws_size,
                              hipStream_t stream) {
  const float* x     = (const float*)d_in[0];
  const float* W_x2h = (const float*)d_in[1];
  const float* b_x2h = (const float*)d_in[2];
  const float* W_h2h = (const float*)d_in[3];
  const float* b_h2h = (const float*)d_in[4];
  const float* W_fc2 = (const float*)d_in[5];
  const float* b_fc2 = (const float*)d_in[6];
  const float* ln_g  = (const float*)d_in[7];
  const float* ln_b  = (const float*)d_in[8];
  const float* W_fcsa= (const float*)d_in[9];
  const float* b_fcsa= (const float*)d_in[10];
  const float* W_in  = (const float*)d_in[11];
  const float* b_in  = (const float*)d_in[12];
  const float* W_out = (const float*)d_in[13];
  const float* b_out = (const float*)d_in[14];
  float* ws = (float*)d_ws;
  float* out = (float*)d_out;

  setup_kernel<<<8, 256, 0, stream>>>(W_x2h,b_x2h,W_h2h,b_h2h,W_fc2,b_fc2,ln_g,ln_b,
                                      W_fcsa,b_fcsa,W_in,b_in,W_out,b_out, ws);
  for (int i=0;i<60;++i){
    int stepB = i-1;
    int stepA = (i<=58)? i : -1;
    const float* qR = ws + OFF_QKV0 + (size_t)((i+1)&1)*QKVN;  // qkv of step i-1
    float*       qW = ws + OFF_QKV0 + (size_t)(i&1)*QKVN;      // qkv of step i
    step_kernel<<<NBLK, TPB, 0, stream>>>(ws, qR, qW, ws+OFF_HNEW, x, out, stepB, stepA);
  }
}